// Round 2
// baseline (2351.262 us; speedup 1.0000x reference)
//
#include <hip/hip_runtime.h>
#include <stdint.h>

// B=256, S=512, ENC=256, DEC=256, ATTN=128, H=48
#define LOG2E 1.4426950408889634f

__device__ __forceinline__ uint32_t bf16r(float x){
  uint32_t u = __float_as_uint(x);
  return (u + 0x7fffu + ((u >> 16) & 1u)) >> 16;   // RNE round to bf16
}
__device__ __forceinline__ uint32_t pack2(float lo, float hi){
  return bf16r(lo) | (bf16r(hi) << 16);
}
__device__ __forceinline__ float unlo(uint32_t u){ return __uint_as_float(u << 16); }
__device__ __forceinline__ float unhi(uint32_t u){ return __uint_as_float(u & 0xffff0000u); }
__device__ __forceinline__ float bf2f(unsigned short w){ return __uint_as_float(((uint32_t)w) << 16); }

__device__ __forceinline__ float fexp2(float x){ return __builtin_amdgcn_exp2f(x); }
__device__ __forceinline__ float frcp(float x){ return __builtin_amdgcn_rcpf(x); }
__device__ __forceinline__ float ftanh(float x){
  float e = fexp2(x * (2.0f * LOG2E));   // exp(2x)
  return 1.0f - 2.0f * frcp(e + 1.0f);
}
__device__ __forceinline__ float fsig(float x){
  return frcp(1.0f + fexp2(-x * LOG2E));
}
__device__ __forceinline__ float wave_max(float x){
  #pragma unroll
  for(int o = 32; o; o >>= 1) x = fmaxf(x, __shfl_xor(x, o, 64));
  return x;
}
__device__ __forceinline__ float wave_sum(float x){
  #pragma unroll
  for(int o = 32; o; o >>= 1) x += __shfl_xor(x, o, 64);
  return x;
}

// -------- K2: pack gate weights for 1024-thread main kernel.
// Thread j of k_main computes gate row j. Wall[k8][j] (uint4, k8<64) packs
// 8 bf16: k8<32 -> W_ih cols 1+8*k8..+7 (ctx part); k8>=32 -> W_hh cols
// 8*(k8-32)..+7. Wp0f[j] = W_ih[j][0] fp32. --------
__global__ __launch_bounds__(256) void k_pack_w(const float* __restrict__ W_ih,
                                                const float* __restrict__ W_hh,
                                                float* __restrict__ Wp0f,
                                                uint4* __restrict__ Wall){
  int gid = blockIdx.x * 256 + threadIdx.x;   // 65536 threads
  if(gid < 1024) Wp0f[gid] = W_ih[gid * 257];
  int k8 = gid >> 10, j = gid & 1023;
  float w[8];
  if(k8 < 32){
    #pragma unroll
    for(int m = 0; m < 8; ++m) w[m] = W_ih[j * 257 + 1 + 8 * k8 + m];
  } else {
    #pragma unroll
    for(int m = 0; m < 8; ++m) w[m] = W_hh[j * 256 + 8 * (k8 - 32) + m];
  }
  Wall[k8 * 1024 + j] = make_uint4(pack2(w[0], w[1]), pack2(w[2], w[3]),
                                   pack2(w[4], w[5]), pack2(w[6], w[7]));
}

// -------- K3: enc_proj = enc @ W_enc (fp32), output bf16 pairs; also emits
// encb (bf16 copy of enc) when ENCB, fused so enc is read once.
// ep layout: [b][a2][s] uint32; encb layout: [b][s][e2] uint32. --------
template<bool ENCB>
__global__ __launch_bounds__(256) void k_enc_proj(const float* __restrict__ enc,
                                                  const float* __restrict__ W_enc,
                                                  uint32_t* __restrict__ ep,
                                                  uint32_t* __restrict__ encb){
  __shared__ float Wl[128][132];   // k-chunk x a (+pad)
  __shared__ float Al[64][132];    // s rows x k-chunk (+pad)
  int tid = threadIdx.x;
  int b = blockIdx.x >> 3;
  int st = (blockIdx.x & 7) * 64;
  int tr = tid & 15, tc = tid >> 4;
  float acc[4][8];
  #pragma unroll
  for(int r = 0; r < 4; ++r)
    #pragma unroll
    for(int i = 0; i < 8; ++i) acc[r][i] = 0.0f;

  if(ENCB){
    const float2* e2p = (const float2*)(enc + ((size_t)(b * 512 + st)) * 256);
    #pragma unroll 4
    for(int i = 0; i < 32; ++i){
      int flat = i * 256 + tid;          // s_off = flat>>7, e2 = flat&127
      float2 f = e2p[flat];
      encb[((size_t)(b * 512 + st) + (flat >> 7)) * 128 + (flat & 127)] = pack2(f.x, f.y);
    }
  }

  for(int kc = 0; kc < 2; ++kc){
    __syncthreads();
    #pragma unroll 8
    for(int i = 0; i < 64; ++i){
      int flat = i * 256 + tid; int kr = flat >> 7, a = flat & 127;
      Wl[kr][a] = W_enc[(kc * 128 + kr) * 128 + a];
    }
    #pragma unroll 8
    for(int i = 0; i < 32; ++i){
      int flat = i * 256 + tid; int row = flat >> 7, col = flat & 127;
      Al[row][col] = enc[((size_t)(b * 512 + st + row)) * 256 + kc * 128 + col];
    }
    __syncthreads();
    for(int k0 = 0; k0 < 128; k0 += 4){
      float4 a0 = *(const float4*)&Al[4 * tc + 0][k0];
      float4 a1 = *(const float4*)&Al[4 * tc + 1][k0];
      float4 a2 = *(const float4*)&Al[4 * tc + 2][k0];
      float4 a3 = *(const float4*)&Al[4 * tc + 3][k0];
      #pragma unroll
      for(int kk = 0; kk < 4; ++kk){
        float4 w0 = *(const float4*)&Wl[k0 + kk][4 * tr];
        float4 w1 = *(const float4*)&Wl[k0 + kk][64 + 4 * tr];
        float av[4];
        av[0] = (&a0.x)[kk]; av[1] = (&a1.x)[kk]; av[2] = (&a2.x)[kk]; av[3] = (&a3.x)[kk];
        #pragma unroll
        for(int r = 0; r < 4; ++r){
          acc[r][0] += av[r] * w0.x; acc[r][1] += av[r] * w0.y;
          acc[r][2] += av[r] * w0.z; acc[r][3] += av[r] * w0.w;
          acc[r][4] += av[r] * w1.x; acc[r][5] += av[r] * w1.y;
          acc[r][6] += av[r] * w1.z; acc[r][7] += av[r] * w1.w;
        }
      }
    }
  }
  #pragma unroll
  for(int r = 0; r < 4; ++r){
    int s = st + 4 * tc + r;
    #pragma unroll
    for(int p = 0; p < 4; ++p){
      int a2i = (p < 2) ? (2 * tr + p) : (32 + 2 * tr + (p - 2));
      ep[((size_t)b * 64 + a2i) * 512 + s] = pack2(acc[r][2 * p], acc[r][2 * p + 1]);
    }
  }
}

// -------- Main: one 1024-thread workgroup per batch element, 48 timesteps.
// 16 waves/CU; __launch_bounds__(1024,4) caps VGPR at 128 so the WG fits. --------
template<bool ENCB>
__global__ __launch_bounds__(1024, 4) void k_main(
    const float* __restrict__ enc,        // fp32 [B][S][ENC]
    const uint32_t* __restrict__ encb,    // bf16 pairs [B][S][128] (if ENCB)
    const uint32_t* __restrict__ ep,      // bf16 pairs [B][64][512]
    const float* __restrict__ h0, const float* __restrict__ c0,
    const float* __restrict__ W_dec, const float* __restrict__ v,
    const float* __restrict__ Wp0f, const uint4* __restrict__ Wall,
    const float* __restrict__ b_ih, const float* __restrict__ b_hh,
    const float* __restrict__ W_out, const float* __restrict__ b_out,
    float* __restrict__ out)
{
  __shared__ unsigned short Wd[128][260];            // W_dec^T bf16 [a][k], +pad
  __shared__ __align__(16) float h_l[256];
  __shared__ __align__(16) float c_l[256];
  __shared__ __align__(16) float ctx[256];
  __shared__ float bcomb[1024];
  __shared__ __align__(16) float4 dvpack[64];        // (dp[2a2], v[2a2], dp[2a2+1], v[2a2+1])
  __shared__ float dpp[8][128];
  __shared__ __align__(16) float4 scp4[8][128];      // score partials [q][sb], rows 4sb..+3
  __shared__ float attn_l[512];
  __shared__ __align__(16) float4 ctxp4[16][64];     // context partials [g][e/4]
  __shared__ float gfull[1024];                      // activated gates
  __shared__ float red1[8], red2[8];
  __shared__ float vl[128], Wo[256];
  __shared__ float misc[2];                          // [0]=prev pred, [1]=b_out

  const int tid = threadIdx.x;
  const int b = blockIdx.x;
  const int lane = tid & 63, wid = tid >> 6;

  // ---- init ----
  #pragma unroll 8
  for(int i = 0; i < 32; ++i){
    int flat = i * 1024 + tid;             // 32768 = 256k x 128a, flat = k*128+a
    Wd[flat & 127][flat >> 7] = (unsigned short)bf16r(W_dec[flat]);
  }
  if(tid < 128) vl[tid] = v[tid];
  if(tid < 256){
    Wo[tid] = W_out[tid];
    h_l[tid] = h0[b * 256 + tid];
    c_l[tid] = c0[b * 256 + tid];
  }
  bcomb[tid] = b_ih[tid] + b_hh[tid];
  float w0r = Wp0f[tid];                   // gate-row col-0 weight, lives in a register
  if(tid == 0){ misc[0] = 0.0f; misc[1] = b_out[0]; }
  __syncthreads();

  const uint32_t* ep_b = ep + (size_t)b * 64 * 512;
  const uint32_t* encb_b = ENCB ? (encb + (size_t)b * 512 * 128) : (const uint32_t*)nullptr;
  const float* enc_b = enc + (size_t)b * 512 * 256;
  const uint4* Wall_t = Wall + tid;
  float* attn_out_b = out + 12288 + (size_t)b * 48 * 512;

  for(int t = 0; t < 48; ++t){
    // ---- P1: dec_proj = h @ W_dec ; thread (a, g): K-range [32g, 32g+32) ----
    {
      int a = tid & 127, g = tid >> 7;
      const float4* h4 = (const float4*)h_l;
      float acc = 0.0f;
      #pragma unroll
      for(int kk = 0; kk < 8; ++kk){
        ushort4 w4 = *(const ushort4*)&Wd[a][g * 32 + kk * 4];
        float4 hh = h4[g * 8 + kk];
        acc += bf2f(w4.x) * hh.x + bf2f(w4.y) * hh.y + bf2f(w4.z) * hh.z + bf2f(w4.w) * hh.w;
      }
      dpp[g][a] = acc;
    }
    __syncthreads();
    if(tid < 64){
      float d0 = 0.0f, d1 = 0.0f;
      #pragma unroll
      for(int g = 0; g < 8; ++g){ d0 += dpp[g][2 * tid]; d1 += dpp[g][2 * tid + 1]; }
      dvpack[tid] = make_float4(d0, vl[2 * tid], d1, vl[2 * tid + 1]);
    }
    __syncthreads();

    // ---- P2: scores ; thread (sb, q): s rows 4sb..+3, a2 in [8q, 8q+8) ----
    {
      int sb = tid & 127, q = tid >> 7;
      float sc0 = 0, sc1 = 0, sc2 = 0, sc3 = 0;
      const uint4* ep4 = (const uint4*)ep_b;   // [a2][128] uint4 (4 s each)
      #pragma unroll
      for(int i = 0; i < 8; ++i){
        int a2 = q * 8 + i;
        uint4 u = ep4[a2 * 128 + sb];
        float4 dv = dvpack[a2];
        sc0 += dv.y * ftanh(unlo(u.x) + dv.x) + dv.w * ftanh(unhi(u.x) + dv.z);
        sc1 += dv.y * ftanh(unlo(u.y) + dv.x) + dv.w * ftanh(unhi(u.y) + dv.z);
        sc2 += dv.y * ftanh(unlo(u.z) + dv.x) + dv.w * ftanh(unhi(u.z) + dv.z);
        sc3 += dv.y * ftanh(unlo(u.w) + dv.x) + dv.w * ftanh(unhi(u.w) + dv.z);
      }
      scp4[q][sb] = make_float4(sc0, sc1, sc2, sc3);
    }
    __syncthreads();

    // ---- P3: softmax over S (threads 0..511 own s=tid; waves 0..7) ----
    float sc_v = 0.0f;
    if(tid < 512){
      const float* scf = (const float*)scp4;   // [q*512 + s]
      #pragma unroll
      for(int q = 0; q < 8; ++q) sc_v += scf[q * 512 + tid];
      float m = wave_max(sc_v);
      if(lane == 0) red1[wid] = m;
    }
    __syncthreads();
    if(tid < 512){
      float M = red1[0];
      #pragma unroll
      for(int i = 1; i < 8; ++i) M = fmaxf(M, red1[i]);
      float w = fexp2((sc_v - M) * LOG2E);
      float sw = wave_sum(w);
      if(lane == 0) red2[wid] = sw;
      sc_v = w;
    }
    __syncthreads();
    if(tid < 512){
      float L = red2[0];
      #pragma unroll
      for(int i = 1; i < 8; ++i) L += red2[i];
      float aw = sc_v * frcp(L);
      attn_l[tid] = aw;
      attn_out_b[t * 512 + tid] = aw;
    }
    __syncthreads();

    // ---- P4: context = attn @ enc ; thread (e4i, g): e=4*e4i..+3, s in [32g, 32g+32) ----
    {
      int e4i = tid & 63, g = tid >> 6;
      float a0 = 0, a1 = 0, a2a = 0, a3 = 0;
      if(ENCB){
        const uint2* eb = (const uint2*)encb_b;
        #pragma unroll 4
        for(int i = 0; i < 32; ++i){
          int s = g * 32 + i;
          float at = attn_l[s];
          uint2 u = eb[(size_t)s * 64 + e4i];
          a0 += at * unlo(u.x); a1 += at * unhi(u.x);
          a2a += at * unlo(u.y); a3 += at * unhi(u.y);
        }
      } else {
        const float4* ef = (const float4*)enc_b;
        #pragma unroll 4
        for(int i = 0; i < 32; ++i){
          int s = g * 32 + i;
          float at = attn_l[s];
          float4 f = ef[(size_t)s * 64 + e4i];
          a0 += at * f.x; a1 += at * f.y; a2a += at * f.z; a3 += at * f.w;
        }
      }
      ctxp4[g][e4i] = make_float4(a0, a1, a2a, a3);
    }
    __syncthreads();
    if(tid < 256){
      const float* cf = (const float*)ctxp4;   // [g*256 + e]
      float s = 0;
      #pragma unroll
      for(int g = 0; g < 16; ++g) s += cf[g * 256 + tid];
      ctx[tid] = s;
    }
    __syncthreads();

    // ---- P5: gates ; thread j computes row j (64 coalesced uint4 weight loads) ----
    {
      float x0v = misc[0];
      float acc = bcomb[tid] + x0v * w0r;
      const float4* c4 = (const float4*)ctx;
      const float4* h4 = (const float4*)h_l;
      #pragma unroll 4
      for(int k8 = 0; k8 < 32; ++k8){
        uint4 q = Wall_t[k8 * 1024];
        float4 x0 = c4[k8 * 2], x1 = c4[k8 * 2 + 1];
        acc += x0.x * unlo(q.x) + x0.y * unhi(q.x) + x0.z * unlo(q.y) + x0.w * unhi(q.y)
             + x1.x * unlo(q.z) + x1.y * unhi(q.z) + x1.z * unlo(q.w) + x1.w * unhi(q.w);
      }
      #pragma unroll 4
      for(int k8 = 32; k8 < 64; ++k8){
        uint4 q = Wall_t[k8 * 1024];
        int kk = k8 - 32;
        float4 x0 = h4[kk * 2], x1 = h4[kk * 2 + 1];
        acc += x0.x * unlo(q.x) + x0.y * unhi(q.x) + x0.z * unlo(q.y) + x0.w * unhi(q.y)
             + x1.x * unlo(q.z) + x1.y * unhi(q.z) + x1.z * unlo(q.w) + x1.w * unhi(q.w);
      }
      // rows: [0,256)=i sig, [256,512)=f sig, [512,768)=g tanh, [768,1024)=o sig
      float act = (tid >= 512 && tid < 768) ? ftanh(acc) : fsig(acc);
      gfull[tid] = act;
    }
    __syncthreads();
    if(tid < 256){
      float ig = gfull[tid], fg = gfull[256 + tid], gg = gfull[512 + tid], og = gfull[768 + tid];
      float cn = fg * c_l[tid] + ig * gg;
      float hn = og * ftanh(cn);
      c_l[tid] = cn; h_l[tid] = hn;
      float p = wave_sum(hn * Wo[tid]);
      if(lane == 0) red1[wid] = p;
    }
    __syncthreads();
    if(tid == 0){
      float pr = red1[0] + red1[1] + red1[2] + red1[3] + misc[1];
      out[b * 48 + t] = pr;
      misc[0] = pr;
    }
    __syncthreads();
  }
}

extern "C" void kernel_launch(void* const* d_in, const int* in_sizes, int n_in,
                              void* d_out, int out_size, void* d_ws, size_t ws_size,
                              hipStream_t stream) {
  (void)in_sizes; (void)n_in; (void)out_size;
  const float* enc  = (const float*)d_in[0];
  const float* h0   = (const float*)d_in[1];
  const float* c0   = (const float*)d_in[2];
  const float* Wenc = (const float*)d_in[3];
  const float* Wdec = (const float*)d_in[4];
  const float* v    = (const float*)d_in[5];
  const float* Wih  = (const float*)d_in[6];
  const float* Whh  = (const float*)d_in[7];
  const float* bih  = (const float*)d_in[8];
  const float* bhh  = (const float*)d_in[9];
  const float* Wout = (const float*)d_in[10];
  const float* bout = (const float*)d_in[11];
  float* out = (float*)d_out;
  uint8_t* ws = (uint8_t*)d_ws;

  const size_t SZ_ENCB = 67108864ull;   // [B][S][128] uint32
  const size_t SZ_EP   = 33554432ull;   // [B][64][512] uint32
  const size_t SZ_WP0  = 4096ull;       // [1024] float
  const size_t SZ_WALL = 1048576ull;    // [64][1024] uint4
  const bool big = ws_size >= SZ_ENCB + SZ_EP + SZ_WP0 + SZ_WALL;

  uint8_t* p = ws;
  uint32_t* encb = nullptr;
  if(big){ encb = (uint32_t*)p; p += SZ_ENCB; }
  uint32_t* ep   = (uint32_t*)p; p += SZ_EP;
  float*    Wp0f = (float*)p;    p += SZ_WP0;
  uint4*    Wall = (uint4*)p;    p += SZ_WALL;

  k_pack_w<<<dim3(256), dim3(256), 0, stream>>>(Wih, Whh, Wp0f, Wall);
  if(big){
    k_enc_proj<true><<<dim3(2048), dim3(256), 0, stream>>>(enc, Wenc, ep, encb);
    k_main<true><<<dim3(256), dim3(1024), 0, stream>>>(enc, encb, ep, h0, c0, Wdec, v,
        Wp0f, Wall, bih, bhh, Wout, bout, out);
  } else {
    k_enc_proj<false><<<dim3(2048), dim3(256), 0, stream>>>(enc, Wenc, ep, nullptr);
    k_main<false><<<dim3(256), dim3(1024), 0, stream>>>(enc, encb, ep, h0, c0, Wdec, v,
        Wp0f, Wall, bih, bhh, Wout, bout, out);
  }
}

// Round 3
// 1669.472 us; speedup vs baseline: 1.4084x; 1.4084x over previous
//
#include <hip/hip_runtime.h>
#include <stdint.h>

// B=256, S=512, ENC=256, DEC=256, ATTN=128, H=48
#define LOG2E 1.4426950408889634f

typedef short v8s __attribute__((ext_vector_type(8)));
typedef float v4f __attribute__((ext_vector_type(4)));

__device__ __forceinline__ uint32_t bf16r(float x){
  uint32_t u = __float_as_uint(x);
  return (u + 0x7fffu + ((u >> 16) & 1u)) >> 16;   // RNE round to bf16
}
__device__ __forceinline__ uint32_t pack2(float lo, float hi){
  return bf16r(lo) | (bf16r(hi) << 16);
}
__device__ __forceinline__ float unlo(uint32_t u){ return __uint_as_float(u << 16); }
__device__ __forceinline__ float unhi(uint32_t u){ return __uint_as_float(u & 0xffff0000u); }

__device__ __forceinline__ float fexp2(float x){ return __builtin_amdgcn_exp2f(x); }
__device__ __forceinline__ float frcp(float x){ return __builtin_amdgcn_rcpf(x); }
__device__ __forceinline__ float ftanh(float x){
  float e = fexp2(x * (2.0f * LOG2E));   // exp(2x)
  return 1.0f - 2.0f * frcp(e + 1.0f);
}
__device__ __forceinline__ float fsig(float x){
  return frcp(1.0f + fexp2(-x * LOG2E));
}
__device__ __forceinline__ float wave_max(float x){
  #pragma unroll
  for(int o = 32; o; o >>= 1) x = fmaxf(x, __shfl_xor(x, o, 64));
  return x;
}
__device__ __forceinline__ float wave_sum(float x){
  #pragma unroll
  for(int o = 32; o; o >>= 1) x += __shfl_xor(x, o, 64);
  return x;
}

// Gate-row interleave: jg in [0,1024) -> actual LSTM row.
// jg = n*64 + dl*4 + gate ; row = gate*256 + n*16 + dl
__device__ __forceinline__ int gate_row(int jg){
  return (jg & 3) * 256 + (jg >> 6) * 16 + ((jg >> 2) & 15);
}

// ---- P0: zero/init workspace state ----
__global__ __launch_bounds__(256) void k_init(const float* __restrict__ c0,
                                              const float* __restrict__ h0,
                                              float* __restrict__ dpp,
                                              float* __restrict__ predp,
                                              float* __restrict__ pred_sum,
                                              float* __restrict__ c_ws,
                                              unsigned short* __restrict__ xcat){
  int gid = blockIdx.x * 256 + threadIdx.x;
  if(gid < 524288){ dpp[gid] = 0.f; return; }          // [256b][16n][128a]
  gid -= 524288;
  if(gid < 4096){ predp[gid] = 0.f; return; }          // [16n][256b]
  gid -= 4096;
  if(gid < 256){ pred_sum[gid] = 0.f; return; }
  gid -= 256;
  if(gid < 65536){ c_ws[gid] = c0[gid]; return; }      // [256b][256d]
  gid -= 65536;
  if(gid < 65536){
    int b = gid >> 8, d = gid & 255;
    xcat[(size_t)b * 512 + 256 + d] = (unsigned short)bf16r(h0[gid]);
  }
}

// ---- P1: pack gate weights bf16, interleaved rows: WmT[jg][k], k<256 ctx, k>=256 h ----
__global__ __launch_bounds__(256) void k_pack(const float* __restrict__ W_ih,
                                              const float* __restrict__ W_hh,
                                              const float* __restrict__ b_ih,
                                              const float* __restrict__ b_hh,
                                              unsigned short* __restrict__ WmT,
                                              float* __restrict__ biasc,
                                              float* __restrict__ w0v){
  int gid = blockIdx.x * 256 + threadIdx.x;   // 65536
  int jg = gid >> 6, k8 = gid & 63;
  int row = gate_row(jg);
  int k0 = k8 * 8;
  uint32_t p[4];
  #pragma unroll
  for(int mm = 0; mm < 4; ++mm){
    int ka = k0 + 2 * mm, kb = ka + 1;
    float lo = (ka < 256) ? W_ih[row * 257 + 1 + ka] : W_hh[row * 256 + (ka - 256)];
    float hi = (kb < 256) ? W_ih[row * 257 + 1 + kb] : W_hh[row * 256 + (kb - 256)];
    p[mm] = pack2(lo, hi);
  }
  *(uint4*)&WmT[(size_t)jg * 512 + k0] = make_uint4(p[0], p[1], p[2], p[3]);
  if(k8 == 0){
    biasc[jg] = b_ih[row] + b_hh[row];
    w0v[jg] = W_ih[row * 257];
  }
}

// ---- P2: enc_proj = enc @ W_enc (fp32) -> ep bf16 pairs [b][a2][s]; fused encb bf16 [b][s][e2] ----
__global__ __launch_bounds__(256) void k_enc_proj(const float* __restrict__ enc,
                                                  const float* __restrict__ W_enc,
                                                  uint32_t* __restrict__ ep,
                                                  uint32_t* __restrict__ encb){
  __shared__ float Wl[128][132];
  __shared__ float Al[64][132];
  int tid = threadIdx.x;
  int b = blockIdx.x >> 3;
  int st = (blockIdx.x & 7) * 64;
  int tr = tid & 15, tc = tid >> 4;
  float acc[4][8];
  #pragma unroll
  for(int r = 0; r < 4; ++r)
    #pragma unroll
    for(int i = 0; i < 8; ++i) acc[r][i] = 0.0f;

  {
    const float2* e2p = (const float2*)(enc + ((size_t)(b * 512 + st)) * 256);
    #pragma unroll 4
    for(int i = 0; i < 32; ++i){
      int flat = i * 256 + tid;
      float2 f = e2p[flat];
      encb[((size_t)(b * 512 + st) + (flat >> 7)) * 128 + (flat & 127)] = pack2(f.x, f.y);
    }
  }

  for(int kc = 0; kc < 2; ++kc){
    __syncthreads();
    #pragma unroll 8
    for(int i = 0; i < 64; ++i){
      int flat = i * 256 + tid; int kr = flat >> 7, a = flat & 127;
      Wl[kr][a] = W_enc[(kc * 128 + kr) * 128 + a];
    }
    #pragma unroll 8
    for(int i = 0; i < 32; ++i){
      int flat = i * 256 + tid; int row = flat >> 7, col = flat & 127;
      Al[row][col] = enc[((size_t)(b * 512 + st + row)) * 256 + kc * 128 + col];
    }
    __syncthreads();
    for(int k0 = 0; k0 < 128; k0 += 4){
      float4 a0 = *(const float4*)&Al[4 * tc + 0][k0];
      float4 a1 = *(const float4*)&Al[4 * tc + 1][k0];
      float4 a2 = *(const float4*)&Al[4 * tc + 2][k0];
      float4 a3 = *(const float4*)&Al[4 * tc + 3][k0];
      #pragma unroll
      for(int kk = 0; kk < 4; ++kk){
        float4 w0 = *(const float4*)&Wl[k0 + kk][4 * tr];
        float4 w1 = *(const float4*)&Wl[k0 + kk][64 + 4 * tr];
        float av[4];
        av[0] = (&a0.x)[kk]; av[1] = (&a1.x)[kk]; av[2] = (&a2.x)[kk]; av[3] = (&a3.x)[kk];
        #pragma unroll
        for(int r = 0; r < 4; ++r){
          acc[r][0] += av[r] * w0.x; acc[r][1] += av[r] * w0.y;
          acc[r][2] += av[r] * w0.z; acc[r][3] += av[r] * w0.w;
          acc[r][4] += av[r] * w1.x; acc[r][5] += av[r] * w1.y;
          acc[r][6] += av[r] * w1.z; acc[r][7] += av[r] * w1.w;
        }
      }
    }
  }
  #pragma unroll
  for(int r = 0; r < 4; ++r){
    int s = st + 4 * tc + r;
    #pragma unroll
    for(int p = 0; p < 4; ++p){
      int a2i = (p < 2) ? (2 * tr + p) : (32 + 2 * tr + (p - 2));
      ep[((size_t)b * 64 + a2i) * 512 + s] = pack2(acc[r][2 * p], acc[r][2 * p + 1]);
    }
  }
}

// ---- P3: dp(t=0) from h0 into dpp slot n=0 (others zeroed by k_init) ----
__global__ __launch_bounds__(128) void k_dp0(const float* __restrict__ h0,
                                             const float* __restrict__ Wdec,
                                             float* __restrict__ dpp){
  int b = blockIdx.x, a = threadIdx.x;
  float acc = 0.f;
  for(int k = 0; k < 256; ++k) acc += h0[b * 256 + k] * Wdec[k * 128 + a];
  dpp[((size_t)b * 16 + 0) * 128 + a] = acc;
}

// ---- K_A (per step): attention for batch b. Reads dpp/predp from k_gates(t-1). ----
__global__ __launch_bounds__(512) void k_attn(
    const uint32_t* __restrict__ encb, const uint32_t* __restrict__ ep,
    const float* __restrict__ dpp, const float* __restrict__ predp,
    const float* __restrict__ v, const float* __restrict__ b_out,
    float* __restrict__ pred_sum, unsigned short* __restrict__ xcat,
    float* __restrict__ out, int t)
{
  __shared__ float dpf[128];
  __shared__ __align__(16) float4 dvpack[64];
  __shared__ __align__(16) float4 scp4[4][128];
  __shared__ float attn_l[512];
  __shared__ __align__(16) float4 ctxp4[8][64];
  __shared__ float ctx[256];
  __shared__ float red1[8], red2[8];
  __shared__ float vl[128];
  const int tid = threadIdx.x, b = blockIdx.x;
  const int lane = tid & 63, wid = tid >> 6;

  if(tid < 128){
    float s = 0.f;
    const float* dpb = dpp + (size_t)b * 2048;
    #pragma unroll
    for(int n = 0; n < 16; ++n) s += dpb[n * 128 + tid];
    dpf[tid] = s;
    vl[tid] = v[tid];
  } else if(tid == 128){
    float pf = 0.f;
    #pragma unroll
    for(int n = 0; n < 16; ++n) pf += predp[n * 256 + b];
    pf += b_out[0];
    if(t > 0){
      out[b * 48 + (t - 1)] = pf;     // finalize previous step's prediction
      pred_sum[b] = pf;               // feeds this step's gates (inp)
    } else {
      pred_sum[b] = 0.f;              // inp0 = zeros
    }
  }
  __syncthreads();
  if(tid < 64)
    dvpack[tid] = make_float4(dpf[2 * tid], vl[2 * tid], dpf[2 * tid + 1], vl[2 * tid + 1]);
  __syncthreads();

  // scores: thread (sb,q): s rows 4sb..+3, a2 in [16q,16q+16)
  {
    int sb = tid & 127, q = tid >> 7;
    float sc0 = 0, sc1 = 0, sc2 = 0, sc3 = 0;
    const uint4* ep4 = (const uint4*)(ep + (size_t)b * 64 * 512);
    #pragma unroll 4
    for(int i = 0; i < 16; ++i){
      int a2 = q * 16 + i;
      uint4 u = ep4[a2 * 128 + sb];
      float4 dv = dvpack[a2];
      sc0 += dv.y * ftanh(unlo(u.x) + dv.x) + dv.w * ftanh(unhi(u.x) + dv.z);
      sc1 += dv.y * ftanh(unlo(u.y) + dv.x) + dv.w * ftanh(unhi(u.y) + dv.z);
      sc2 += dv.y * ftanh(unlo(u.z) + dv.x) + dv.w * ftanh(unhi(u.z) + dv.z);
      sc3 += dv.y * ftanh(unlo(u.w) + dv.x) + dv.w * ftanh(unhi(u.w) + dv.z);
    }
    scp4[q][sb] = make_float4(sc0, sc1, sc2, sc3);
  }
  __syncthreads();

  // softmax over S (thread owns s=tid)
  float sc;
  {
    const float* scf = (const float*)scp4;
    sc = scf[tid] + scf[512 + tid] + scf[1024 + tid] + scf[1536 + tid];
    float m = wave_max(sc);
    if(lane == 0) red1[wid] = m;
  }
  __syncthreads();
  float M = red1[0];
  #pragma unroll
  for(int i = 1; i < 8; ++i) M = fmaxf(M, red1[i]);
  float w = fexp2((sc - M) * LOG2E);
  {
    float sw = wave_sum(w);
    if(lane == 0) red2[wid] = sw;
  }
  __syncthreads();
  float L = red2[0];
  #pragma unroll
  for(int i = 1; i < 8; ++i) L += red2[i];
  float aw = w * frcp(L);
  attn_l[tid] = aw;
  out[12288 + (size_t)b * 48 * 512 + t * 512 + tid] = aw;
  __syncthreads();

  // context: thread (e4i,g): e=4*e4i..+3, s in [64g,64g+64)
  {
    int e4i = tid & 63, g = tid >> 6;
    float a0 = 0, a1 = 0, a2a = 0, a3 = 0;
    const uint2* eb = (const uint2*)(encb + (size_t)b * 512 * 128);
    #pragma unroll 4
    for(int i = 0; i < 64; ++i){
      int s = g * 64 + i;
      float at = attn_l[s];
      uint2 u = eb[(size_t)s * 64 + e4i];
      a0 += at * unlo(u.x); a1 += at * unhi(u.x);
      a2a += at * unlo(u.y); a3 += at * unhi(u.y);
    }
    ctxp4[g][e4i] = make_float4(a0, a1, a2a, a3);
  }
  __syncthreads();
  if(tid < 256){
    const float* cf = (const float*)ctxp4;
    float s = 0;
    #pragma unroll
    for(int g = 0; g < 8; ++g) s += cf[g * 256 + tid];
    ctx[tid] = s;
  }
  __syncthreads();
  if(tid < 128)
    *(uint32_t*)&xcat[(size_t)b * 512 + 2 * tid] = pack2(ctx[2 * tid], ctx[2 * tid + 1]);
}

// ---- K_B (per step): gates GEMM (MFMA) + LSTM pointwise + dp/pred partials.
// Grid 256: m=bx>>4 (b-tile of 16), n=bx&15 (16 d / 64 interleaved gate rows). ----
__global__ __launch_bounds__(256) void k_gates(
    const unsigned short* __restrict__ WmT, const float* __restrict__ biasc,
    const float* __restrict__ w0v, const float* __restrict__ pred_sum,
    const float* __restrict__ Wdec, const float* __restrict__ Wout,
    float* __restrict__ c_ws, unsigned short* __restrict__ xcat,
    float* __restrict__ dpp, float* __restrict__ predp)
{
  __shared__ unsigned short WT[64][520];   // weight rows jg-local, k; +16B pad
  __shared__ unsigned short AT[16][520];   // xcat rows b-local
  __shared__ float WdecL[16][128];
  __shared__ float gact[64][20];           // activated gates [j-local][b-local]
  __shared__ float hl[16][17];
  const int tid = threadIdx.x;
  const int m = blockIdx.x >> 4, n = blockIdx.x & 15;

  // stage weights (64 rows x 512 bf16 = 64 KB)
  {
    const uint4* src = (const uint4*)(WmT + (size_t)(n * 64) * 512);
    #pragma unroll
    for(int i = 0; i < 16; ++i){
      int flat = i * 256 + tid;            // 4096 uint4
      int r = flat >> 6, q = flat & 63;
      *(uint4*)&WT[r][q * 8] = src[r * 64 + q];
    }
  }
  // stage A (16 rows x 512 bf16 = 16 KB): xcat rows m*16..+15 ({ctx|h} bf16)
  {
    const uint4* src = (const uint4*)(xcat + (size_t)(m * 16) * 512);
    #pragma unroll
    for(int i = 0; i < 4; ++i){
      int flat = i * 256 + tid;            // 1024 uint4
      int r = flat >> 6, q = flat & 63;
      *(uint4*)&AT[r][q * 8] = src[r * 64 + q];
    }
  }
  // stage Wdec rows d = 16n..+15 (8 KB)
  {
    const float4* src = (const float4*)(Wdec + (size_t)(n * 16) * 128);
    #pragma unroll
    for(int i = 0; i < 2; ++i){
      int flat = i * 256 + tid;            // 512 float4
      int r = flat >> 5, q = flat & 31;
      *(float4*)&WdecL[r][q * 4] = src[r * 32 + q];
    }
  }
  __syncthreads();

  // MFMA: wave wv owns 16x16 D-tile (rows=b-local, cols=j-local wv*16..+15)
  const int lane = tid & 63, wv = tid >> 6;
  const int quad = lane >> 4, rr = lane & 15;
  const int jl = wv * 16 + rr;             // B row for this lane (n-index = rr)
  v4f acc = {0.f, 0.f, 0.f, 0.f};
  #pragma unroll
  for(int kt = 0; kt < 16; ++kt){
    int k0 = kt * 32 + quad * 8;
    v8s av = *(const v8s*)&AT[rr][k0];     // A[m=rr][k0..k0+7]
    v8s bv = *(const v8s*)&WT[jl][k0];     // B[k][n=rr] = W[jl][k]
    acc = __builtin_amdgcn_mfma_f32_16x16x32_bf16(av, bv, acc, 0, 0, 0);
  }
  // epilogue: bias + pred*w0, activation; D row = quad*4+reg (b-local), col = rr (j-local)
  {
    int jg = n * 64 + jl;
    float bias = biasc[jg];
    float w0 = w0v[jg];
    int gate = jl & 3;
    float4 g4;
    #pragma unroll
    for(int r = 0; r < 4; ++r){
      int bl = quad * 4 + r;
      float pre = acc[r] + bias + pred_sum[m * 16 + bl] * w0;
      (&g4.x)[r] = (gate == 2) ? ftanh(pre) : fsig(pre);
    }
    *(float4*)&gact[jl][quad * 4] = g4;
  }
  __syncthreads();

  // pointwise LSTM update: thread (bl, dl) for tid<256
  if(tid < 256){
    int bl = tid >> 4, dl = tid & 15;
    float gi = gact[dl * 4 + 0][bl];
    float gf = gact[dl * 4 + 1][bl];
    float gg = gact[dl * 4 + 2][bl];
    float go = gact[dl * 4 + 3][bl];
    int bg = m * 16 + bl, dg = n * 16 + dl;
    size_t cidx = (size_t)bg * 256 + dg;
    float cn = gf * c_ws[cidx] + gi * gg;
    float hn = go * ftanh(cn);
    c_ws[cidx] = cn;
    xcat[(size_t)bg * 512 + 256 + dg] = (unsigned short)bf16r(hn);
    hl[bl][dl] = hn;
    float pp = hn * Wout[dg];
    #pragma unroll
    for(int o = 8; o; o >>= 1) pp += __shfl_xor(pp, o, 64);  // reduce over dl (low 4 lane bits)
    if(dl == 0) predp[n * 256 + bg] = pp;
  }
  __syncthreads();

  // dp partial for next step: dpp[bg][n][a] = sum_d hl[bl][d]*Wdec[d][a]
  if(tid < 256){
    int bl = tid >> 4, ag = tid & 15;
    int bg = m * 16 + bl;
    float a0[8] = {0, 0, 0, 0, 0, 0, 0, 0};
    #pragma unroll
    for(int d = 0; d < 16; ++d){
      float hv = hl[bl][d];
      #pragma unroll
      for(int j = 0; j < 8; ++j) a0[j] += hv * WdecL[d][ag * 8 + j];
    }
    float* dst = dpp + ((size_t)bg * 16 + n) * 128 + ag * 8;
    *(float4*)dst = make_float4(a0[0], a0[1], a0[2], a0[3]);
    *(float4*)(dst + 4) = make_float4(a0[4], a0[5], a0[6], a0[7]);
  }
}

// ---- tail: finalize t=47 prediction ----
__global__ __launch_bounds__(256) void k_tail(const float* __restrict__ predp,
                                              const float* __restrict__ b_out,
                                              float* __restrict__ out){
  int b = threadIdx.x;
  float pf = 0.f;
  #pragma unroll
  for(int n = 0; n < 16; ++n) pf += predp[n * 256 + b];
  out[b * 48 + 47] = pf + b_out[0];
}

extern "C" void kernel_launch(void* const* d_in, const int* in_sizes, int n_in,
                              void* d_out, int out_size, void* d_ws, size_t ws_size,
                              hipStream_t stream) {
  (void)in_sizes; (void)n_in; (void)out_size; (void)ws_size;
  const float* enc  = (const float*)d_in[0];
  const float* h0   = (const float*)d_in[1];
  const float* c0   = (const float*)d_in[2];
  const float* Wenc = (const float*)d_in[3];
  const float* Wdec = (const float*)d_in[4];
  const float* v    = (const float*)d_in[5];
  const float* Wih  = (const float*)d_in[6];
  const float* Whh  = (const float*)d_in[7];
  const float* bih  = (const float*)d_in[8];
  const float* bhh  = (const float*)d_in[9];
  const float* Wout = (const float*)d_in[10];
  const float* bout = (const float*)d_in[11];
  float* out = (float*)d_out;
  uint8_t* p = (uint8_t*)d_ws;

  uint32_t* encb = (uint32_t*)p;        p += 67108864ull;   // [256][512][128] u32
  uint32_t* ep   = (uint32_t*)p;        p += 33554432ull;   // [256][64][512] u32
  unsigned short* WmT = (unsigned short*)p; p += 1048576ull; // [1024][512] bf16
  float* biasc  = (float*)p;            p += 4096ull;
  float* w0v    = (float*)p;            p += 4096ull;
  float* dpp    = (float*)p;            p += 2097152ull;    // [256][16][128] f32
  float* predp  = (float*)p;            p += 16384ull;      // [16][256] f32
  float* pred_s = (float*)p;            p += 1024ull;       // [256] f32
  unsigned short* xcat = (unsigned short*)p; p += 262144ull; // [256][512] bf16
  float* c_ws   = (float*)p;            p += 262144ull;     // [256][256] f32

  k_init<<<dim3(2577), dim3(256), 0, stream>>>(c0, h0, dpp, predp, pred_s, c_ws, xcat);
  k_pack<<<dim3(256), dim3(256), 0, stream>>>(Wih, Whh, bih, bhh, WmT, biasc, w0v);
  k_enc_proj<<<dim3(2048), dim3(256), 0, stream>>>(enc, Wenc, ep, encb);
  k_dp0<<<dim3(256), dim3(128), 0, stream>>>(h0, Wdec, dpp);

  for(int t = 0; t < 48; ++t){
    k_attn<<<dim3(256), dim3(512), 0, stream>>>(encb, ep, dpp, predp, v, bout,
                                                pred_s, xcat, out, t);
    k_gates<<<dim3(256), dim3(256), 0, stream>>>(WmT, biasc, w0v, pred_s, Wdec, Wout,
                                                 c_ws, xcat, dpp, predp);
  }
  k_tail<<<dim3(1), dim3(256), 0, stream>>>(predp, bout, out);
}

// Round 5
// 1602.095 us; speedup vs baseline: 1.4676x; 1.0421x over previous
//
#include <hip/hip_runtime.h>
#include <stdint.h>

// B=256, S=512, ENC=256, DEC=256, ATTN=128, H=48
#define LOG2E 1.4426950408889634f

typedef short v8s __attribute__((ext_vector_type(8)));
typedef float v4f __attribute__((ext_vector_type(4)));

__device__ __forceinline__ uint32_t bf16r(float x){
  uint32_t u = __float_as_uint(x);
  return (u + 0x7fffu + ((u >> 16) & 1u)) >> 16;   // RNE round to bf16
}
__device__ __forceinline__ uint32_t pack2(float lo, float hi){
  return bf16r(lo) | (bf16r(hi) << 16);
}
__device__ __forceinline__ float unlo(uint32_t u){ return __uint_as_float(u << 16); }
__device__ __forceinline__ float unhi(uint32_t u){ return __uint_as_float(u & 0xffff0000u); }

__device__ __forceinline__ float fexp2(float x){ return __builtin_amdgcn_exp2f(x); }
__device__ __forceinline__ float frcp(float x){ return __builtin_amdgcn_rcpf(x); }
__device__ __forceinline__ float ftanh(float x){
  float e = fexp2(x * (2.0f * LOG2E));   // exp(2x)
  return 1.0f - 2.0f * frcp(e + 1.0f);
}
__device__ __forceinline__ float fsig(float x){
  return frcp(1.0f + fexp2(-x * LOG2E));
}
__device__ __forceinline__ float wave_sum(float x){
  #pragma unroll
  for(int o = 32; o; o >>= 1) x += __shfl_xor(x, o, 64);
  return x;
}

// Gate-row interleave: jg = n*64 + dl*4 + gate ; row = gate*256 + n*16 + dl
__device__ __forceinline__ int gate_row(int jg){
  return (jg & 3) * 256 + (jg >> 6) * 16 + ((jg >> 2) & 15);
}

// ---- P0: zero/init workspace state ----
__global__ __launch_bounds__(256) void k_init(const float* __restrict__ c0,
                                              const float* __restrict__ h0,
                                              float* __restrict__ dpp,
                                              float* __restrict__ predp,
                                              float* __restrict__ pred_sum,
                                              float* __restrict__ c_ws,
                                              unsigned short* __restrict__ xcat){
  int gid = blockIdx.x * 256 + threadIdx.x;
  if(gid < 524288){ dpp[gid] = 0.f; return; }          // [256b][16n][128a]
  gid -= 524288;
  if(gid < 4096){ predp[gid] = 0.f; return; }          // [16n][256b]
  gid -= 4096;
  if(gid < 256){ pred_sum[gid] = 0.f; return; }
  gid -= 256;
  if(gid < 65536){ c_ws[gid] = c0[gid]; return; }      // [256b][256d]
  gid -= 65536;
  if(gid < 65536){
    int b = gid >> 8, d = gid & 255;
    xcat[(size_t)b * 512 + 256 + d] = (unsigned short)bf16r(h0[gid]);
  }
}

// ---- P1: pack gate weights bf16 (interleaved rows) + WencT split hi/lo bf16 ----
__global__ __launch_bounds__(256) void k_pack(const float* __restrict__ W_ih,
                                              const float* __restrict__ W_hh,
                                              const float* __restrict__ b_ih,
                                              const float* __restrict__ b_hh,
                                              const float* __restrict__ W_enc,
                                              unsigned short* __restrict__ WmT,
                                              float* __restrict__ biasc,
                                              float* __restrict__ w0v,
                                              unsigned short* __restrict__ WencTh,
                                              unsigned short* __restrict__ WencTl){
  int gid = blockIdx.x * 256 + threadIdx.x;   // 98304
  if(gid < 65536){
    int jg = gid >> 6, k8 = gid & 63;
    int row = gate_row(jg);
    int k0 = k8 * 8;
    uint32_t p[4];
    #pragma unroll
    for(int mm = 0; mm < 4; ++mm){
      int ka = k0 + 2 * mm, kb = ka + 1;
      float lo = (ka < 256) ? W_ih[row * 257 + 1 + ka] : W_hh[row * 256 + (ka - 256)];
      float hi = (kb < 256) ? W_ih[row * 257 + 1 + kb] : W_hh[row * 256 + (kb - 256)];
      p[mm] = pack2(lo, hi);
    }
    *(uint4*)&WmT[(size_t)jg * 512 + k0] = make_uint4(p[0], p[1], p[2], p[3]);
    if(k8 == 0){
      biasc[jg] = b_ih[row] + b_hh[row];
      w0v[jg] = W_ih[row * 257];
    }
  } else {
    int g2 = gid - 65536;                    // 32768 = 256k x 128a
    int k = g2 >> 7, a = g2 & 127;
    float x = W_enc[k * 128 + a];
    uint32_t hb = bf16r(x);
    WencTh[a * 256 + k] = (unsigned short)hb;
    float hv = __uint_as_float(hb << 16);
    WencTl[a * 256 + k] = (unsigned short)bf16r(x - hv);
  }
}

// ---- P2: enc_proj via MFMA bf16 with split hi/lo inputs (near-fp32 precision).
// Grid 1024 = (b, mt); 256 threads (4 waves). Block (b,mt): s-rows [128mt,+128),
// all 128 a, K=256 in 8 chunks of 32. ep = Ah*Wh + Al*Wh + Ah*Wl (fp32 acc).
// Outputs: ep bf16 [b][a][s] and encb bf16-pairs [b][s][e2] (fused conversion). ----
__global__ __launch_bounds__(256, 2) void k_enc_proj(const float* __restrict__ enc,
                                                     const unsigned short* __restrict__ WencTh,
                                                     const unsigned short* __restrict__ WencTl,
                                                     unsigned short* __restrict__ ep,
                                                     uint32_t* __restrict__ encb){
  __shared__ unsigned short Ash[128][48];  // [s-local][k-chunk] hi
  __shared__ unsigned short Asl[128][48];  // lo
  __shared__ unsigned short Wth[128][48];  // [a][k-chunk] hi
  __shared__ unsigned short Wtl[128][48];  // lo
  const int tid = threadIdx.x;
  const int b = blockIdx.x >> 2, mt = blockIdx.x & 3;
  const int lane = tid & 63, w = tid >> 6;
  const int rr = lane & 15, quad = lane >> 4;

  v4f acc[2][8];
  #pragma unroll
  for(int g = 0; g < 2; ++g)
    #pragma unroll
    for(int nt = 0; nt < 8; ++nt) acc[g][nt] = (v4f){0.f, 0.f, 0.f, 0.f};

  const float* encBase = enc + ((size_t)(b * 512 + mt * 128)) * 256;
  uint32_t* encbBase = encb + ((size_t)(b * 512 + mt * 128)) * 128;

  for(int kt = 0; kt < 8; ++kt){
    __syncthreads();
    // stage A rows: fp32 -> (hi, lo) bf16 + fused encb emit (hi)
    #pragma unroll
    for(int i = 0; i < 4; ++i){
      int flat = i * 256 + tid;              // 1024 = 128 rows x 8 float4
      int row = flat >> 3, c4 = flat & 7;
      float4 f = *(const float4*)(encBase + (size_t)row * 256 + kt * 32 + c4 * 4);
      uint32_t hx = bf16r(f.x), hy = bf16r(f.y), hz = bf16r(f.z), hw = bf16r(f.w);
      uint2 hp = make_uint2(hx | (hy << 16), hz | (hw << 16));
      float lx = f.x - __uint_as_float(hx << 16);
      float ly = f.y - __uint_as_float(hy << 16);
      float lz = f.z - __uint_as_float(hz << 16);
      float lw = f.w - __uint_as_float(hw << 16);
      uint2 lp = make_uint2(pack2(lx, ly), pack2(lz, lw));
      *(uint2*)&Ash[row][c4 * 4] = hp;
      *(uint2*)&Asl[row][c4 * 4] = lp;
      *(uint2*)&encbBase[(size_t)row * 128 + kt * 16 + c4 * 2] = hp;
    }
    // stage Wt hi/lo from preconverted split transpose
    #pragma unroll
    for(int i = 0; i < 2; ++i){
      int flat = i * 256 + tid;              // 512 = 128 a x 4 uint4
      int a = flat >> 2, q4 = flat & 3;
      *(uint4*)&Wth[a][q4 * 8] = *(const uint4*)(WencTh + (size_t)a * 256 + kt * 32 + q4 * 8);
      *(uint4*)&Wtl[a][q4 * 8] = *(const uint4*)(WencTl + (size_t)a * 256 + kt * 32 + q4 * 8);
    }
    __syncthreads();
    // MFMA: wave w covers s-rows [32w, 32w+32) as two 16-row groups; 3 products
    #pragma unroll
    for(int g = 0; g < 2; ++g){
      v8s ah = *(const v8s*)&Ash[32 * w + 16 * g + rr][quad * 8];
      v8s al = *(const v8s*)&Asl[32 * w + 16 * g + rr][quad * 8];
      #pragma unroll
      for(int nt = 0; nt < 8; ++nt){
        v8s bh = *(const v8s*)&Wth[nt * 16 + rr][quad * 8];
        v8s bl = *(const v8s*)&Wtl[nt * 16 + rr][quad * 8];
        acc[g][nt] = __builtin_amdgcn_mfma_f32_16x16x32_bf16(ah, bh, acc[g][nt], 0, 0, 0);
        acc[g][nt] = __builtin_amdgcn_mfma_f32_16x16x32_bf16(al, bh, acc[g][nt], 0, 0, 0);
        acc[g][nt] = __builtin_amdgcn_mfma_f32_16x16x32_bf16(ah, bl, acc[g][nt], 0, 0, 0);
      }
    }
  }
  // store ep: lane holds a = nt*16+rr, s = 128mt+32w+16g+quad*4+r (r=0..3)
  #pragma unroll
  for(int g = 0; g < 2; ++g){
    int s0 = 128 * mt + 32 * w + 16 * g + quad * 4;
    #pragma unroll
    for(int nt = 0; nt < 8; ++nt){
      int a = nt * 16 + rr;
      uint2 pp = make_uint2(pack2(acc[g][nt][0], acc[g][nt][1]),
                            pack2(acc[g][nt][2], acc[g][nt][3]));
      *(uint2*)&ep[((size_t)b * 128 + a) * 512 + s0] = pp;
    }
  }
}

// ---- P3: dp(t=0) from h0 into dpp slot n=0 ----
__global__ __launch_bounds__(128) void k_dp0(const float* __restrict__ h0,
                                             const float* __restrict__ Wdec,
                                             float* __restrict__ dpp){
  int b = blockIdx.x, a = threadIdx.x;
  float acc = 0.f;
  for(int k = 0; k < 256; ++k) acc += h0[b * 256 + k] * Wdec[k * 128 + a];
  dpp[((size_t)b * 16 + 0) * 128 + a] = acc;
}

// ---- K_A (per step): attention for batch b ----
__global__ __launch_bounds__(512) void k_attn(
    const uint32_t* __restrict__ encb, const unsigned short* __restrict__ ep,
    const float* __restrict__ dpp, const float* __restrict__ predp,
    const float* __restrict__ v, const float* __restrict__ b_out,
    float* __restrict__ pred_sum, unsigned short* __restrict__ xcat,
    float* __restrict__ out, int t)
{
  __shared__ float dpf[128], vl[128];
  __shared__ float scp[512][9];              // [s][q], stride 9
  __shared__ float attn_l[512];
  __shared__ float ctxp[16][256];            // [g][e]
  __shared__ float ctx[256];
  __shared__ float red2[8];
  const int tid = threadIdx.x, b = blockIdx.x;
  const int lane = tid & 63, wid = tid >> 6;

  if(tid < 128){
    float s = 0.f;
    const float* dpb = dpp + (size_t)b * 2048;
    #pragma unroll
    for(int n = 0; n < 16; ++n) s += dpb[n * 128 + tid];
    dpf[tid] = s;
    vl[tid] = v[tid];
  } else if(tid == 128){
    float pf = 0.f;
    #pragma unroll
    for(int n = 0; n < 16; ++n) pf += predp[n * 256 + b];
    pf += b_out[0];
    if(t > 0){
      out[b * 48 + (t - 1)] = pf;
      pred_sum[b] = pf;
    } else {
      pred_sum[b] = 0.f;
    }
  }
  __syncthreads();

  // scores: thread (sb=lane over 64, q=wave): s = sb*8+j, a in [16q,16q+16)
  {
    int sb = tid & 63, q = tid >> 6;
    float sc[8];
    #pragma unroll
    for(int j = 0; j < 8; ++j) sc[j] = 0.f;
    const uint4* ep4 = (const uint4*)(ep + (size_t)b * 65536);
    #pragma unroll 4
    for(int i = 0; i < 16; ++i){
      int a = q * 16 + i;
      uint4 u = ep4[a * 64 + sb];            // 8 bf16 s-values for one a
      float dd = dpf[a], vv = vl[a];
      sc[0] += vv * ftanh(unlo(u.x) + dd);
      sc[1] += vv * ftanh(unhi(u.x) + dd);
      sc[2] += vv * ftanh(unlo(u.y) + dd);
      sc[3] += vv * ftanh(unhi(u.y) + dd);
      sc[4] += vv * ftanh(unlo(u.z) + dd);
      sc[5] += vv * ftanh(unhi(u.z) + dd);
      sc[6] += vv * ftanh(unlo(u.w) + dd);
      sc[7] += vv * ftanh(unhi(u.w) + dd);
    }
    #pragma unroll
    for(int j = 0; j < 8; ++j) scp[sb * 8 + j][q] = sc[j];
  }
  __syncthreads();

  // softmax over S — max-free: |score| <= ||v||_1 ~ 5, fp32 exp safe
  float w;
  {
    float s = 0.f;
    #pragma unroll
    for(int q = 0; q < 8; ++q) s += scp[tid][q];
    w = fexp2(s * LOG2E);
    float sw = wave_sum(w);
    if(lane == 0) red2[wid] = sw;
  }
  __syncthreads();
  {
    float L = red2[0];
    #pragma unroll
    for(int i = 1; i < 8; ++i) L += red2[i];
    float aw = w * frcp(L);
    attn_l[tid] = aw;
    out[12288 + (size_t)b * 24576 + t * 512 + tid] = aw;
  }
  __syncthreads();

  // context: thread (e4=tid&31, g=tid>>5): 8 e-values, s in [32g,32g+32)
  {
    int e4 = tid & 31, g = tid >> 5;
    float a8[8];
    #pragma unroll
    for(int j = 0; j < 8; ++j) a8[j] = 0.f;
    const uint4* eb = (const uint4*)(encb + (size_t)b * 65536);
    #pragma unroll 4
    for(int i = 0; i < 32; ++i){
      int s = g * 32 + i;
      float at = attn_l[s];
      uint4 u = eb[s * 32 + e4];
      a8[0] += at * unlo(u.x); a8[1] += at * unhi(u.x);
      a8[2] += at * unlo(u.y); a8[3] += at * unhi(u.y);
      a8[4] += at * unlo(u.z); a8[5] += at * unhi(u.z);
      a8[6] += at * unlo(u.w); a8[7] += at * unhi(u.w);
    }
    #pragma unroll
    for(int j = 0; j < 8; ++j) ctxp[g][e4 * 8 + j] = a8[j];
  }
  __syncthreads();
  if(tid < 256){
    float s = 0.f;
    #pragma unroll
    for(int g = 0; g < 16; ++g) s += ctxp[g][tid];
    ctx[tid] = s;
  }
  __syncthreads();
  if(tid < 128)
    *(uint32_t*)&xcat[(size_t)b * 512 + 2 * tid] = pack2(ctx[2 * tid], ctx[2 * tid + 1]);
}

// ---- K_B (per step): gates GEMM (MFMA) + LSTM pointwise + dp/pred partials ----
__global__ __launch_bounds__(256) void k_gates(
    const unsigned short* __restrict__ WmT, const float* __restrict__ biasc,
    const float* __restrict__ w0v, const float* __restrict__ pred_sum,
    const float* __restrict__ Wdec, const float* __restrict__ Wout,
    float* __restrict__ c_ws, unsigned short* __restrict__ xcat,
    float* __restrict__ dpp, float* __restrict__ predp)
{
  __shared__ unsigned short WT[64][520];
  __shared__ unsigned short AT[16][520];
  __shared__ float WdecL[16][128];
  __shared__ float gact[64][20];
  __shared__ float hl[16][17];
  const int tid = threadIdx.x;
  const int m = blockIdx.x >> 4, n = blockIdx.x & 15;

  {
    const uint4* src = (const uint4*)(WmT + (size_t)(n * 64) * 512);
    #pragma unroll
    for(int i = 0; i < 16; ++i){
      int flat = i * 256 + tid;
      int r = flat >> 6, q = flat & 63;
      *(uint4*)&WT[r][q * 8] = src[r * 64 + q];
    }
  }
  {
    const uint4* src = (const uint4*)(xcat + (size_t)(m * 16) * 512);
    #pragma unroll
    for(int i = 0; i < 4; ++i){
      int flat = i * 256 + tid;
      int r = flat >> 6, q = flat & 63;
      *(uint4*)&AT[r][q * 8] = src[r * 64 + q];
    }
  }
  {
    const float4* src = (const float4*)(Wdec + (size_t)(n * 16) * 128);
    #pragma unroll
    for(int i = 0; i < 2; ++i){
      int flat = i * 256 + tid;
      int r = flat >> 5, q = flat & 31;
      *(float4*)&WdecL[r][q * 4] = src[r * 32 + q];
    }
  }
  __syncthreads();

  const int lane = tid & 63, wv = tid >> 6;
  const int quad = lane >> 4, rr = lane & 15;
  const int jl = wv * 16 + rr;
  v4f acc = {0.f, 0.f, 0.f, 0.f};
  #pragma unroll
  for(int kt = 0; kt < 16; ++kt){
    int k0 = kt * 32 + quad * 8;
    v8s av = *(const v8s*)&AT[rr][k0];
    v8s bv = *(const v8s*)&WT[jl][k0];
    acc = __builtin_amdgcn_mfma_f32_16x16x32_bf16(av, bv, acc, 0, 0, 0);
  }
  {
    int jg = n * 64 + jl;
    float bias = biasc[jg];
    float w0 = w0v[jg];
    int gate = jl & 3;
    float4 g4;
    #pragma unroll
    for(int r = 0; r < 4; ++r){
      int bl = quad * 4 + r;
      float pre = acc[r] + bias + pred_sum[m * 16 + bl] * w0;
      (&g4.x)[r] = (gate == 2) ? ftanh(pre) : fsig(pre);
    }
    *(float4*)&gact[jl][quad * 4] = g4;
  }
  __syncthreads();

  if(tid < 256){
    int bl = tid >> 4, dl = tid & 15;
    float gi = gact[dl * 4 + 0][bl];
    float gf = gact[dl * 4 + 1][bl];
    float gg = gact[dl * 4 + 2][bl];
    float go = gact[dl * 4 + 3][bl];
    int bg = m * 16 + bl, dg = n * 16 + dl;
    size_t cidx = (size_t)bg * 256 + dg;
    float cn = gf * c_ws[cidx] + gi * gg;
    float hn = go * ftanh(cn);
    c_ws[cidx] = cn;
    xcat[(size_t)bg * 512 + 256 + dg] = (unsigned short)bf16r(hn);
    hl[bl][dl] = hn;
    float pp = hn * Wout[dg];
    #pragma unroll
    for(int o = 8; o; o >>= 1) pp += __shfl_xor(pp, o, 64);
    if(dl == 0) predp[n * 256 + bg] = pp;
  }
  __syncthreads();

  if(tid < 256){
    int bl = tid >> 4, ag = tid & 15;
    int bg = m * 16 + bl;
    float a0[8] = {0, 0, 0, 0, 0, 0, 0, 0};
    #pragma unroll
    for(int d = 0; d < 16; ++d){
      float hv = hl[bl][d];
      #pragma unroll
      for(int j = 0; j < 8; ++j) a0[j] += hv * WdecL[d][ag * 8 + j];
    }
    float* dst = dpp + ((size_t)bg * 16 + n) * 128 + ag * 8;
    *(float4*)dst = make_float4(a0[0], a0[1], a0[2], a0[3]);
    *(float4*)(dst + 4) = make_float4(a0[4], a0[5], a0[6], a0[7]);
  }
}

// ---- tail: finalize t=47 prediction ----
__global__ __launch_bounds__(256) void k_tail(const float* __restrict__ predp,
                                              const float* __restrict__ b_out,
                                              float* __restrict__ out){
  int b = threadIdx.x;
  float pf = 0.f;
  #pragma unroll
  for(int n = 0; n < 16; ++n) pf += predp[n * 256 + b];
  out[b * 48 + 47] = pf + b_out[0];
}

extern "C" void kernel_launch(void* const* d_in, const int* in_sizes, int n_in,
                              void* d_out, int out_size, void* d_ws, size_t ws_size,
                              hipStream_t stream) {
  (void)in_sizes; (void)n_in; (void)out_size; (void)ws_size;
  const float* enc  = (const float*)d_in[0];
  const float* h0   = (const float*)d_in[1];
  const float* c0   = (const float*)d_in[2];
  const float* Wenc = (const float*)d_in[3];
  const float* Wdec = (const float*)d_in[4];
  const float* v    = (const float*)d_in[5];
  const float* Wih  = (const float*)d_in[6];
  const float* Whh  = (const float*)d_in[7];
  const float* bih  = (const float*)d_in[8];
  const float* bhh  = (const float*)d_in[9];
  const float* Wout = (const float*)d_in[10];
  const float* bout = (const float*)d_in[11];
  float* out = (float*)d_out;
  uint8_t* p = (uint8_t*)d_ws;

  uint32_t* encb = (uint32_t*)p;            p += 67108864ull;  // [256][512][128] u32 pairs
  unsigned short* ep = (unsigned short*)p;  p += 33554432ull;  // [256][128][512] bf16
  unsigned short* WmT = (unsigned short*)p; p += 1048576ull;   // [1024][512] bf16
  float* biasc  = (float*)p;                p += 4096ull;
  float* w0v    = (float*)p;                p += 4096ull;
  unsigned short* WencTh = (unsigned short*)p; p += 131072ull; // [128][256] bf16 hi
  unsigned short* WencTl = (unsigned short*)p; p += 131072ull; // [128][256] bf16 lo
  float* dpp    = (float*)p;                p += 2097152ull;   // [256][16][128] f32
  float* predp  = (float*)p;                p += 16384ull;     // [16][256] f32
  float* pred_s = (float*)p;                p += 1024ull;      // [256] f32
  unsigned short* xcat = (unsigned short*)p; p += 262144ull;   // [256][512] bf16
  float* c_ws   = (float*)p;                p += 262144ull;    // [256][256] f32

  k_init<<<dim3(2577), dim3(256), 0, stream>>>(c0, h0, dpp, predp, pred_s, c_ws, xcat);
  k_pack<<<dim3(384), dim3(256), 0, stream>>>(Wih, Whh, bih, bhh, Wenc, WmT, biasc, w0v,
                                              WencTh, WencTl);
  k_enc_proj<<<dim3(1024), dim3(256), 0, stream>>>(enc, WencTh, WencTl, ep, encb);
  k_dp0<<<dim3(256), dim3(128), 0, stream>>>(h0, Wdec, dpp);

  for(int t = 0; t < 48; ++t){
    k_attn<<<dim3(256), dim3(512), 0, stream>>>(encb, ep, dpp, predp, v, bout,
                                                pred_s, xcat, out, t);
    k_gates<<<dim3(256), dim3(256), 0, stream>>>(WmT, biasc, w0v, pred_s, Wdec, Wout,
                                                 c_ws, xcat, dpp, predp);
  }
  k_tail<<<dim3(1), dim3(256), 0, stream>>>(predp, bout, out);
}